// Round 2
// baseline (5053.636 us; speedup 1.0000x reference)
//
#include <hip/hip_runtime.h>
#include <hip/hip_bf16.h>

#define B_ 32
#define T_ 512
#define D_ 1024
#define HOP_ 8
#define HID_ 350
#define NEGV -1e30f
#define CH_ 4  // batches per chunk

__device__ __forceinline__ float fast_sigmoid(float x) {
    return 1.0f / (1.0f + __expf(-x));
}
__device__ __forceinline__ float fast_tanh(float x) {
    return 1.0f - 2.0f / (__expf(2.0f * x) + 1.0f);
}

// ---------------- lengths ----------------
__global__ __launch_bounds__(512) void lengths_k(const float* __restrict__ input,
                                                 int* __restrict__ len) {
    int b = blockIdx.x;
    int t = threadIdx.x;
    int z = (input[((size_t)b * T_ + t) * D_] == 0.0f) ? 1 : 0;
    __shared__ int cnt;
    if (t == 0) cnt = 0;
    __syncthreads();
    unsigned long long m = __ballot(z);
    if ((t & 63) == 0) atomicAdd(&cnt, __popcll(m));
    __syncthreads();
    if (t == 0) len[b] = T_ - cnt;
}

// ---------------- generic fp32 GEMM, 64x64 tile, BK=16, 4x4/thread --------
// BT=false: Bm is (K,N) row-major.  BT=true: Bm is (N,K) row-major.
// Requires: M % 64 == 0, K % 16 == 0. N guarded.
template <bool BT, bool DO_TANH>
__global__ __launch_bounds__(256) void gemm64(const float* __restrict__ A,
                                              const float* __restrict__ Bm,
                                              float* __restrict__ C,
                                              int M, int N, int K) {
    __shared__ float As[16][64];
    __shared__ float Bs[16][64];
    const int tid = threadIdx.x;
    const int tx = tid & 15;   // N dir
    const int ty = tid >> 4;   // M dir
    const int m0 = blockIdx.y * 64;
    const int n0 = blockIdx.x * 64;
    float acc[4][4] = {};
    const int ar = tid >> 2;          // 0..63 (A row)
    const int ac = (tid & 3) << 2;    // 0,4,8,12 (A k)

    for (int k0 = 0; k0 < K; k0 += 16) {
        {
            float4 v = *(const float4*)&A[(size_t)(m0 + ar) * K + k0 + ac];
            As[ac + 0][ar] = v.x; As[ac + 1][ar] = v.y;
            As[ac + 2][ar] = v.z; As[ac + 3][ar] = v.w;
        }
        if (!BT) {
            int kk = tid >> 4;          // 0..15
            int c4 = (tid & 15) << 2;   // 0..60
            float4 v = *(const float4*)&Bm[(size_t)(k0 + kk) * N + n0 + c4];
            Bs[kk][c4 + 0] = v.x; Bs[kk][c4 + 1] = v.y;
            Bs[kk][c4 + 2] = v.z; Bs[kk][c4 + 3] = v.w;
        } else {
            int nn = tid >> 2;          // 0..63
            int kk = (tid & 3) << 2;
            int row = n0 + nn;
            if (row < N) {
                float4 v = *(const float4*)&Bm[(size_t)row * K + k0 + kk];
                Bs[kk + 0][nn] = v.x; Bs[kk + 1][nn] = v.y;
                Bs[kk + 2][nn] = v.z; Bs[kk + 3][nn] = v.w;
            } else {
                Bs[kk + 0][nn] = 0.f; Bs[kk + 1][nn] = 0.f;
                Bs[kk + 2][nn] = 0.f; Bs[kk + 3][nn] = 0.f;
            }
        }
        __syncthreads();
#pragma unroll
        for (int kk = 0; kk < 16; ++kk) {
            float4 a = *(const float4*)&As[kk][ty << 2];
            float4 b = *(const float4*)&Bs[kk][tx << 2];
            float am[4] = {a.x, a.y, a.z, a.w};
            float bm[4] = {b.x, b.y, b.z, b.w};
#pragma unroll
            for (int i = 0; i < 4; ++i)
#pragma unroll
                for (int j = 0; j < 4; ++j)
                    acc[i][j] += am[i] * bm[j];
        }
        __syncthreads();
    }
#pragma unroll
    for (int i = 0; i < 4; ++i) {
        int row = m0 + (ty << 2) + i;
#pragma unroll
        for (int j = 0; j < 4; ++j) {
            int col = n0 + (tx << 2) + j;
            if (col < N) {
                float v = acc[i][j];
                if (DO_TANH) v = fast_tanh(v);
                C[(size_t)row * N + col] = v;
            }
        }
    }
}

// ---------------- SRU recurrence: thread per (b,d), 8-step load groups ----
__global__ __launch_bounds__(256) void sru_scan(const float* __restrict__ U,
                                                const float* __restrict__ bias,
                                                const float* __restrict__ xin,
                                                float* __restrict__ xout) {
    int idx = blockIdx.x * 256 + threadIdx.x;  // (local b)*D + d
    int b = idx >> 10;
    int d = idx & (D_ - 1);
    float bf = bias[d], br = bias[D_ + d];
    float c = 0.0f;
    const float* Ub = U + (size_t)b * T_ * (3 * D_);
    const float* xb = xin + (size_t)b * T_ * D_;
    float* ob = xout + (size_t)b * T_ * D_;
    for (int t = 0; t < T_; t += 8) {
        float ux[8], uf[8], ur[8], xv[8];
#pragma unroll
        for (int j = 0; j < 8; ++j) {
            const float* u = Ub + (size_t)(t + j) * (3 * D_);
            ux[j] = u[d];
            uf[j] = u[D_ + d];
            ur[j] = u[2 * D_ + d];
            xv[j] = xb[(size_t)(t + j) * D_ + d];
        }
#pragma unroll
        for (int j = 0; j < 8; ++j) {
            float f = fast_sigmoid(uf[j] + bf);
            float r = fast_sigmoid(ur[j] + br);
            c = f * c + (1.0f - f) * ux[j];
            ob[(size_t)(t + j) * D_ + d] = r * fast_tanh(c) + (1.0f - r) * xv[j];
        }
    }
}

// ---------------- alphas: thread per (b,t), 8 heads streamed --------------
__global__ __launch_bounds__(256) void alphas_k(const float* __restrict__ hbar,
                                                const float* __restrict__ ws2,
                                                float* __restrict__ alph) {
    __shared__ float w[HOP_][352];
    for (int i = threadIdx.x; i < HOP_ * HID_; i += 256)
        w[i / HID_][i % HID_] = ws2[i];
    __syncthreads();
    int bt = blockIdx.x * 256 + threadIdx.x;  // 0..16383
    const float* hr = hbar + (size_t)bt * HID_;
    float acc[HOP_] = {};
    for (int h = 0; h < HID_; ++h) {
        float hv = hr[h];
#pragma unroll
        for (int k = 0; k < HOP_; ++k) acc[k] += w[k][h] * hv;
    }
    float* ar = alph + (size_t)bt * HOP_;
#pragma unroll
    for (int k = 0; k < HOP_; ++k) ar[k] = acc[k];
}

// ---------------- masked softmax over t, block per (b,k) ----------------
__global__ __launch_bounds__(256) void softmax_k(const float* __restrict__ alph,
                                                 const int* __restrict__ len,
                                                 float* __restrict__ attn) {
    int b = blockIdx.x >> 3, k = blockIdx.x & 7;
    int L = len[b];
    int t0 = threadIdx.x, t1 = threadIdx.x + 256;
    float v0 = (t0 >= L) ? NEGV : alph[((size_t)b * T_ + t0) * HOP_ + k];
    float v1 = (t1 >= L) ? NEGV : alph[((size_t)b * T_ + t1) * HOP_ + k];
    __shared__ float redm[4];
    __shared__ float reds[4];
    float m = fmaxf(v0, v1);
#pragma unroll
    for (int off = 32; off; off >>= 1) m = fmaxf(m, __shfl_xor(m, off));
    if ((threadIdx.x & 63) == 0) redm[threadIdx.x >> 6] = m;
    __syncthreads();
    m = fmaxf(fmaxf(redm[0], redm[1]), fmaxf(redm[2], redm[3]));
    float e0 = __expf(v0 - m), e1 = __expf(v1 - m);
    float s = e0 + e1;
#pragma unroll
    for (int off = 32; off; off >>= 1) s += __shfl_xor(s, off);
    if ((threadIdx.x & 63) == 0) reds[threadIdx.x >> 6] = s;
    __syncthreads();
    s = reds[0] + reds[1] + reds[2] + reds[3];
    float inv = 1.0f / s;
    float* ar = attn + ((size_t)b * HOP_ + k) * T_;
    ar[t0] = e0 * inv;
    ar[t1] = e1 * inv;
}

// ---------------- pooled[b,k,d] = sum_t attn[b,k,t] * x2[b,t,d] -----------
__global__ __launch_bounds__(256) void pooled_k(const float* __restrict__ attn,
                                                const float* __restrict__ x2,
                                                float* __restrict__ pooled) {
    __shared__ float at[HOP_][T_];  // 16 KB
    int b = blockIdx.x >> 2;
    int d0 = (blockIdx.x & 3) * 256;
    for (int i = threadIdx.x; i < HOP_ * T_; i += 256)
        at[i >> 9][i & (T_ - 1)] = attn[(size_t)b * HOP_ * T_ + i];
    __syncthreads();
    int d = d0 + threadIdx.x;
    float acc[HOP_] = {};
    const float* xb = x2 + (size_t)b * T_ * D_ + d;
    for (int t = 0; t < T_; ++t) {
        float xv = xb[(size_t)t * D_];
#pragma unroll
        for (int k = 0; k < HOP_; ++k) acc[k] += at[k][t] * xv;
    }
#pragma unroll
    for (int k = 0; k < HOP_; ++k)
        pooled[((size_t)b * HOP_ + k) * D_ + d] = acc[k];
}

// ---------------- fc: out[b,j] = pooled[b,:] . fc_w[j,:] + fc_b[j] --------
__global__ __launch_bounds__(256) void fc_k(const float* __restrict__ pooled,
                                            const float* __restrict__ fcw,
                                            const float* __restrict__ fcb,
                                            float* __restrict__ out) {
    __shared__ float w[8][1028];  // +4 pad: conflict-free, 16B aligned
    int j0 = blockIdx.x * 8;
    int b = threadIdx.x >> 3, jj = threadIdx.x & 7;
    float acc = 0.0f;
    for (int p0 = 0; p0 < HOP_ * D_; p0 += 1024) {
        __syncthreads();
        for (int i = threadIdx.x * 4; i < 8 * 1024; i += 256 * 4) {
            int r = i >> 10, c = i & 1023;
            *(float4*)&w[r][c] = *(const float4*)&fcw[(size_t)(j0 + r) * (HOP_ * D_) + p0 + c];
        }
        __syncthreads();
        const float* pr = pooled + (size_t)b * (HOP_ * D_) + p0;
#pragma unroll 4
        for (int i = 0; i < 1024; i += 4) {
            float4 wv = *(const float4*)&w[jj][i];
            float4 pv = *(const float4*)&pr[i];
            acc += wv.x * pv.x + wv.y * pv.y + wv.z * pv.z + wv.w * pv.w;
        }
    }
    out[(size_t)b * D_ + j0 + jj] = acc + fcb[j0 + jj];
}

extern "C" void kernel_launch(void* const* d_in, const int* in_sizes, int n_in,
                              void* d_out, int out_size, void* d_ws, size_t ws_size,
                              hipStream_t stream) {
    const float* input = (const float*)d_in[0];
    // d_in[1] = lg (unused; reference ignores it)
    const float* W0   = (const float*)d_in[2];
    const float* b0   = (const float*)d_in[3];
    const float* W1   = (const float*)d_in[4];
    const float* b1   = (const float*)d_in[5];
    const float* ws1  = (const float*)d_in[6];
    const float* ws2  = (const float*)d_in[7];
    const float* fc_w = (const float*)d_in[8];
    const float* fc_b = (const float*)d_in[9];

    float* out  = (float*)d_out;                 // (B, D) = 32768 floats
    float* attn = out + (size_t)B_ * D_;         // (B, HOP, T) = 131072 floats

    // ---- workspace layout (chunked; ~96 MB total) ----
    // [0, 25165824)            U_chunk fp32 (CH*512*3072)
    // [25165824, 33554432)     x1_chunk fp32 (CH*512*1024)
    // [33554432, 100663296)    x2 fp32 full (32*512*1024)
    // [100663296, 100663424)   len (int[32])
    // After chunks done, U region is reused: hbar | alph | pooled
    const size_t NEED = 100663424;
    if (ws_size < NEED) return;  // clean diagnostic fail (absmax = max|ref|)

    char* ws = (char*)d_ws;
    float* U    = (float*)ws;
    float* x1c  = (float*)(ws + 25165824);
    float* x2   = (float*)(ws + 33554432);
    int*   len  = (int*)(ws + 100663296);
    float* hbar   = (float*)ws;                    // 16384*350*4 = 22937600
    float* alph   = (float*)(ws + 22937600);       // 524288
    float* pooled = (float*)(ws + 23461888);       // 1048576 (ends 24510464 < 25165824)
    (void)in_sizes; (void)n_in; (void)out_size;

    lengths_k<<<B_, 512, 0, stream>>>(input, len);

    const int Mc = CH_ * T_;  // 2048 rows per chunk
    for (int c0 = 0; c0 < B_; c0 += CH_) {
        const float* inC = input + (size_t)c0 * T_ * D_;
        float* x2C = x2 + (size_t)c0 * T_ * D_;
        // Layer 1
        gemm64<false, false><<<dim3(3 * D_ / 64, Mc / 64), 256, 0, stream>>>(
            inC, W0, U, Mc, 3 * D_, D_);
        sru_scan<<<CH_ * D_ / 256, 256, 0, stream>>>(U, b0, inC, x1c);
        // Layer 2
        gemm64<false, false><<<dim3(3 * D_ / 64, Mc / 64), 256, 0, stream>>>(
            x1c, W1, U, Mc, 3 * D_, D_);
        sru_scan<<<CH_ * D_ / 256, 256, 0, stream>>>(U, b1, x1c, x2C);
    }

    const int M = B_ * T_;
    // hbar = tanh(x2 @ ws1^T), N=350
    gemm64<true, true><<<dim3((HID_ + 63) / 64, M / 64), 256, 0, stream>>>(
        x2, ws1, hbar, M, HID_, D_);

    alphas_k<<<M / 256, 256, 0, stream>>>(hbar, ws2, alph);
    softmax_k<<<B_ * HOP_, 256, 0, stream>>>(alph, len, attn);
    pooled_k<<<B_ * 4, 256, 0, stream>>>(attn, x2, pooled);
    fc_k<<<D_ / 8, 256, 0, stream>>>(pooled, fc_w, fc_b, out);
}

// Round 3
// 4987.975 us; speedup vs baseline: 1.0132x; 1.0132x over previous
//
#include <hip/hip_runtime.h>
#include <hip/hip_bf16.h>

#define B_ 32
#define T_ 512
#define D_ 1024
#define HOP_ 8
#define HID_ 350
#define NEGV -1e30f
#define CH_ 4  // batches per chunk (fallback path)

typedef __bf16 v8bf __attribute__((ext_vector_type(8)));
typedef float  v4f  __attribute__((ext_vector_type(4)));

__device__ __forceinline__ float fast_sigmoid(float x) {
    return 1.0f / (1.0f + __expf(-x));
}
__device__ __forceinline__ float fast_tanh(float x) {
    return 1.0f - 2.0f / (__expf(2.0f * x) + 1.0f);
}
__device__ __forceinline__ float bf2f(unsigned short u) {
    unsigned x = ((unsigned)u) << 16;
    float f;
    __builtin_memcpy(&f, &x, 4);
    return f;
}
__device__ __forceinline__ unsigned short f2bf(float v) {
    __hip_bfloat16 h = __float2bfloat16(v);
    unsigned short u;
    __builtin_memcpy(&u, &h, 2);
    return u;
}

// ---------------- lengths ----------------
__global__ __launch_bounds__(512) void lengths_k(const float* __restrict__ input,
                                                 int* __restrict__ len) {
    int b = blockIdx.x;
    int t = threadIdx.x;
    int z = (input[((size_t)b * T_ + t) * D_] == 0.0f) ? 1 : 0;
    __shared__ int cnt;
    if (t == 0) cnt = 0;
    __syncthreads();
    unsigned long long m = __ballot(z);
    if ((t & 63) == 0) atomicAdd(&cnt, __popcll(m));
    __syncthreads();
    if (t == 0) len[b] = T_ - cnt;
}

// =================== FAST PATH (bf16 MFMA) ===================

// fp32 -> bf16 rowmajor copy (vector 4)
__global__ __launch_bounds__(256) void convX_k(const float* __restrict__ in,
                                               unsigned short* __restrict__ out) {
    int i = (blockIdx.x * 256 + threadIdx.x) * 4;
    float4 v = *(const float4*)&in[i];
    out[i + 0] = f2bf(v.x);
    out[i + 1] = f2bf(v.y);
    out[i + 2] = f2bf(v.z);
    out[i + 3] = f2bf(v.w);
}

// weight -> tiled bf16 layout [kb][nb][n:128][k:32]
// NT=false: W is (K,N) row-major. NT=true: W is (Nreal,K) row-major, zero-pad n>=Nreal.
template <bool NT>
__global__ __launch_bounds__(256) void convW_k(const float* __restrict__ W,
                                               unsigned short* __restrict__ Wp,
                                               int K, int N, int nT, int Nreal) {
    int o = blockIdx.x * 256 + threadIdx.x;
    int tile = o >> 13;          // 8192 elems per tile
    int within = o & 8191;
    int n_l = within >> 5, k_l = within & 31;
    int kb = tile / nT, nbb = tile % nT;
    int n = nbb * 128 + n_l, k = kb * 32 + k_l;
    float v = 0.f;
    if (NT) {
        if (n < Nreal) v = W[(size_t)n * K + k];
    } else {
        v = W[(size_t)k * N + n];
    }
    Wp[o] = f2bf(v);
}

// MFMA GEMM: C = A(M,K) @ B(K,N), 128x128 tile, BK=32, 4 waves of 64x64.
// EPI 0: SRU epilogue -> bf16 U' (stride 3072), sigmoid+bias for cols >= 1024.
// EPI 1: tanh epilogue -> fp32 C (stride Nstore), guard col < Nstore.
template <int EPI>
__global__ __launch_bounds__(256) void gemm_mfma(
    const unsigned short* __restrict__ A,
    const unsigned short* __restrict__ Bp,
    const float* __restrict__ bias,
    void* __restrict__ C,
    int K, int nT, int Nstore) {
    __shared__ __align__(16) unsigned short As[128 * 32];
    __shared__ __align__(16) unsigned short Bs[128 * 32];
    const int tid = threadIdx.x;
    const int lane = tid & 63;
    const int wid = __builtin_amdgcn_readfirstlane(tid >> 6);
    const int wm = wid & 1, wn = wid >> 1;
    const int m0 = blockIdx.y * 128;
    const int n0 = blockIdx.x * 128;
    const int nb = blockIdx.x;
    const int quad = lane >> 4;
    const int l15 = lane & 15;

    v4f acc[4][4];
#pragma unroll
    for (int i = 0; i < 4; ++i)
#pragma unroll
        for (int j = 0; j < 4; ++j) acc[i][j] = (v4f)(0.f);

    const int nKB = K >> 5;
    for (int kb = 0; kb < nKB; ++kb) {
        __syncthreads();
        // stage A: 128 rows x 32 k = 512 x 16B granules; granule g -> row g>>2, kpart g&3
#pragma unroll
        for (int p = 0; p < 2; ++p) {
            int g = p * 256 + wid * 64 + lane;
            const unsigned short* gp = A + (size_t)(m0 + (g >> 2)) * K + kb * 32 + (g & 3) * 8;
            int ldsOff = (p * 256 + wid * 64) * 16;
            __builtin_amdgcn_global_load_lds(
                (const __attribute__((address_space(1))) void*)gp,
                (__attribute__((address_space(3))) void*)((char*)As + ldsOff),
                16, 0, 0);
        }
        // stage B: linear copy of pre-tiled 16KB-like block (8KB here)
        const unsigned short* bt = Bp + (size_t)(kb * nT + nb) * (128 * 32);
#pragma unroll
        for (int p = 0; p < 2; ++p) {
            int g = p * 256 + wid * 64 + lane;
            const unsigned short* gp = bt + g * 8;
            int ldsOff = (p * 256 + wid * 64) * 16;
            __builtin_amdgcn_global_load_lds(
                (const __attribute__((address_space(1))) void*)gp,
                (__attribute__((address_space(3))) void*)((char*)Bs + ldsOff),
                16, 0, 0);
        }
        __syncthreads();
        v8bf af[4], bf[4];
#pragma unroll
        for (int mi = 0; mi < 4; ++mi)
            af[mi] = *(const v8bf*)&As[(wm * 64 + mi * 16 + l15) * 32 + quad * 8];
#pragma unroll
        for (int ni = 0; ni < 4; ++ni)
            bf[ni] = *(const v8bf*)&Bs[(wn * 64 + ni * 16 + l15) * 32 + quad * 8];
#pragma unroll
        for (int mi = 0; mi < 4; ++mi)
#pragma unroll
            for (int ni = 0; ni < 4; ++ni)
                acc[mi][ni] = __builtin_amdgcn_mfma_f32_16x16x32_bf16(
                    af[mi], bf[ni], acc[mi][ni], 0, 0, 0);
    }

    const int baseM = m0 + wm * 64;
    const int baseN = n0 + wn * 64;
    if (EPI == 0) {
        unsigned short* Up = (unsigned short*)C;
#pragma unroll
        for (int ni = 0; ni < 4; ++ni) {
            int j = baseN + ni * 16 + l15;
            bool sig = j >= 1024;
            float bv = sig ? bias[j - 1024] : 0.f;
#pragma unroll
            for (int mi = 0; mi < 4; ++mi) {
                int m = baseM + mi * 16 + quad * 4;
                v4f c = acc[mi][ni];
#pragma unroll
                for (int r = 0; r < 4; ++r) {
                    float v = c[r];
                    if (sig) v = fast_sigmoid(v + bv);
                    Up[(size_t)(m + r) * 3072 + j] = f2bf(v);
                }
            }
        }
    } else {
        float* Cf = (float*)C;
#pragma unroll
        for (int ni = 0; ni < 4; ++ni) {
            int j = baseN + ni * 16 + l15;
            if (j < Nstore) {
#pragma unroll
                for (int mi = 0; mi < 4; ++mi) {
                    int m = baseM + mi * 16 + quad * 4;
                    v4f c = acc[mi][ni];
#pragma unroll
                    for (int r = 0; r < 4; ++r)
                        Cf[(size_t)(m + r) * Nstore + j] = fast_tanh(c[r]);
                }
            }
        }
    }
}

// SRU scan over bf16 U' = {xt, f=sigmoid'd, r=sigmoid'd}; writes fp32 + bf16 x.
__global__ __launch_bounds__(64) void sru_scan_bf(const unsigned short* __restrict__ Up,
                                                  const float* __restrict__ xin,
                                                  float* __restrict__ xout,
                                                  unsigned short* __restrict__ xoutb) {
    int idx = blockIdx.x * 64 + threadIdx.x;  // b*D + d
    int b = idx >> 10, d = idx & (D_ - 1);
    const unsigned short* Ub = Up + (size_t)b * T_ * 3072 + d;
    const float* xb = xin + (size_t)b * T_ * D_ + d;
    float* ob = xout + (size_t)b * T_ * D_ + d;
    unsigned short* obb = xoutb + (size_t)b * T_ * D_ + d;
    float c = 0.f;
    for (int t = 0; t < T_; t += 8) {
        float xt[8], f[8], r[8], xv[8];
#pragma unroll
        for (int j = 0; j < 8; ++j) {
            const unsigned short* u = Ub + (size_t)(t + j) * 3072;
            xt[j] = bf2f(u[0]);
            f[j] = bf2f(u[1024]);
            r[j] = bf2f(u[2048]);
            xv[j] = xb[(size_t)(t + j) * D_];
        }
#pragma unroll
        for (int j = 0; j < 8; ++j) {
            c = f[j] * c + (1.f - f[j]) * xt[j];
            float o = r[j] * fast_tanh(c) + (1.f - r[j]) * xv[j];
            ob[(size_t)(t + j) * D_] = o;
            obb[(size_t)(t + j) * D_] = f2bf(o);
        }
    }
}

// =================== FALLBACK PATH (fp32, chunked; round-2 proven) ===================

template <bool BT, bool DO_TANH>
__global__ __launch_bounds__(256) void gemm64(const float* __restrict__ A,
                                              const float* __restrict__ Bm,
                                              float* __restrict__ C,
                                              int M, int N, int K) {
    __shared__ float Asm[16][64];
    __shared__ float Bsm[16][64];
    const int tid = threadIdx.x;
    const int tx = tid & 15;
    const int ty = tid >> 4;
    const int m0 = blockIdx.y * 64;
    const int n0 = blockIdx.x * 64;
    float acc[4][4] = {};
    const int ar = tid >> 2;
    const int ac = (tid & 3) << 2;

    for (int k0 = 0; k0 < K; k0 += 16) {
        {
            float4 v = *(const float4*)&A[(size_t)(m0 + ar) * K + k0 + ac];
            Asm[ac + 0][ar] = v.x; Asm[ac + 1][ar] = v.y;
            Asm[ac + 2][ar] = v.z; Asm[ac + 3][ar] = v.w;
        }
        if (!BT) {
            int kk = tid >> 4;
            int c4 = (tid & 15) << 2;
            float4 v = *(const float4*)&Bm[(size_t)(k0 + kk) * N + n0 + c4];
            Bsm[kk][c4 + 0] = v.x; Bsm[kk][c4 + 1] = v.y;
            Bsm[kk][c4 + 2] = v.z; Bsm[kk][c4 + 3] = v.w;
        } else {
            int nn = tid >> 2;
            int kk = (tid & 3) << 2;
            int row = n0 + nn;
            if (row < N) {
                float4 v = *(const float4*)&Bm[(size_t)row * K + k0 + kk];
                Bsm[kk + 0][nn] = v.x; Bsm[kk + 1][nn] = v.y;
                Bsm[kk + 2][nn] = v.z; Bsm[kk + 3][nn] = v.w;
            } else {
                Bsm[kk + 0][nn] = 0.f; Bsm[kk + 1][nn] = 0.f;
                Bsm[kk + 2][nn] = 0.f; Bsm[kk + 3][nn] = 0.f;
            }
        }
        __syncthreads();
#pragma unroll
        for (int kk = 0; kk < 16; ++kk) {
            float4 a = *(const float4*)&Asm[kk][ty << 2];
            float4 b = *(const float4*)&Bsm[kk][tx << 2];
            float am[4] = {a.x, a.y, a.z, a.w};
            float bm[4] = {b.x, b.y, b.z, b.w};
#pragma unroll
            for (int i = 0; i < 4; ++i)
#pragma unroll
                for (int j = 0; j < 4; ++j)
                    acc[i][j] += am[i] * bm[j];
        }
        __syncthreads();
    }
#pragma unroll
    for (int i = 0; i < 4; ++i) {
        int row = m0 + (ty << 2) + i;
#pragma unroll
        for (int j = 0; j < 4; ++j) {
            int col = n0 + (tx << 2) + j;
            if (col < N) {
                float v = acc[i][j];
                if (DO_TANH) v = fast_tanh(v);
                C[(size_t)row * N + col] = v;
            }
        }
    }
}

__global__ __launch_bounds__(256) void sru_scan(const float* __restrict__ U,
                                                const float* __restrict__ bias,
                                                const float* __restrict__ xin,
                                                float* __restrict__ xout) {
    int idx = blockIdx.x * 256 + threadIdx.x;
    int b = idx >> 10;
    int d = idx & (D_ - 1);
    float bfv = bias[d], br = bias[D_ + d];
    float c = 0.0f;
    const float* Ub = U + (size_t)b * T_ * (3 * D_);
    const float* xb = xin + (size_t)b * T_ * D_;
    float* ob = xout + (size_t)b * T_ * D_;
    for (int t = 0; t < T_; t += 8) {
        float ux[8], uf[8], ur[8], xv[8];
#pragma unroll
        for (int j = 0; j < 8; ++j) {
            const float* u = Ub + (size_t)(t + j) * (3 * D_);
            ux[j] = u[d];
            uf[j] = u[D_ + d];
            ur[j] = u[2 * D_ + d];
            xv[j] = xb[(size_t)(t + j) * D_ + d];
        }
#pragma unroll
        for (int j = 0; j < 8; ++j) {
            float f = fast_sigmoid(uf[j] + bfv);
            float r = fast_sigmoid(ur[j] + br);
            c = f * c + (1.0f - f) * ux[j];
            ob[(size_t)(t + j) * D_ + d] = r * fast_tanh(c) + (1.0f - r) * xv[j];
        }
    }
}

// =================== shared tail kernels ===================

__global__ __launch_bounds__(256) void alphas_k(const float* __restrict__ hbar,
                                                const float* __restrict__ ws2,
                                                float* __restrict__ alph) {
    __shared__ float w[HOP_][352];
    for (int i = threadIdx.x; i < HOP_ * HID_; i += 256)
        w[i / HID_][i % HID_] = ws2[i];
    __syncthreads();
    int bt = blockIdx.x * 256 + threadIdx.x;
    const float* hr = hbar + (size_t)bt * HID_;
    float acc[HOP_] = {};
    for (int h = 0; h < HID_; ++h) {
        float hv = hr[h];
#pragma unroll
        for (int k = 0; k < HOP_; ++k) acc[k] += w[k][h] * hv;
    }
    float* ar = alph + (size_t)bt * HOP_;
#pragma unroll
    for (int k = 0; k < HOP_; ++k) ar[k] = acc[k];
}

__global__ __launch_bounds__(256) void softmax_k(const float* __restrict__ alph,
                                                 const int* __restrict__ len,
                                                 float* __restrict__ attn) {
    int b = blockIdx.x >> 3, k = blockIdx.x & 7;
    int L = len[b];
    int t0 = threadIdx.x, t1 = threadIdx.x + 256;
    float v0 = (t0 >= L) ? NEGV : alph[((size_t)b * T_ + t0) * HOP_ + k];
    float v1 = (t1 >= L) ? NEGV : alph[((size_t)b * T_ + t1) * HOP_ + k];
    __shared__ float redm[4];
    __shared__ float reds[4];
    float m = fmaxf(v0, v1);
#pragma unroll
    for (int off = 32; off; off >>= 1) m = fmaxf(m, __shfl_xor(m, off));
    if ((threadIdx.x & 63) == 0) redm[threadIdx.x >> 6] = m;
    __syncthreads();
    m = fmaxf(fmaxf(redm[0], redm[1]), fmaxf(redm[2], redm[3]));
    float e0 = __expf(v0 - m), e1 = __expf(v1 - m);
    float s = e0 + e1;
#pragma unroll
    for (int off = 32; off; off >>= 1) s += __shfl_xor(s, off);
    if ((threadIdx.x & 63) == 0) reds[threadIdx.x >> 6] = s;
    __syncthreads();
    s = reds[0] + reds[1] + reds[2] + reds[3];
    float inv = 1.0f / s;
    float* ar = attn + ((size_t)b * HOP_ + k) * T_;
    ar[t0] = e0 * inv;
    ar[t1] = e1 * inv;
}

__global__ __launch_bounds__(256) void pooled_k(const float* __restrict__ attn,
                                                const float* __restrict__ x2,
                                                float* __restrict__ pooled) {
    __shared__ float at[HOP_][T_];
    int b = blockIdx.x >> 2;
    int d0 = (blockIdx.x & 3) * 256;
    for (int i = threadIdx.x; i < HOP_ * T_; i += 256)
        at[i >> 9][i & (T_ - 1)] = attn[(size_t)b * HOP_ * T_ + i];
    __syncthreads();
    int d = d0 + threadIdx.x;
    float acc[HOP_] = {};
    const float* xb = x2 + (size_t)b * T_ * D_ + d;
    for (int t = 0; t < T_; ++t) {
        float xv = xb[(size_t)t * D_];
#pragma unroll
        for (int k = 0; k < HOP_; ++k) acc[k] += at[k][t] * xv;
    }
#pragma unroll
    for (int k = 0; k < HOP_; ++k)
        pooled[((size_t)b * HOP_ + k) * D_ + d] = acc[k];
}

__global__ __launch_bounds__(256) void fc_k(const float* __restrict__ pooled,
                                            const float* __restrict__ fcw,
                                            const float* __restrict__ fcb,
                                            float* __restrict__ out) {
    __shared__ float w[8][1028];
    int j0 = blockIdx.x * 8;
    int b = threadIdx.x >> 3, jj = threadIdx.x & 7;
    float acc = 0.0f;
    for (int p0 = 0; p0 < HOP_ * D_; p0 += 1024) {
        __syncthreads();
        for (int i = threadIdx.x * 4; i < 8 * 1024; i += 256 * 4) {
            int r = i >> 10, c = i & 1023;
            *(float4*)&w[r][c] = *(const float4*)&fcw[(size_t)(j0 + r) * (HOP_ * D_) + p0 + c];
        }
        __syncthreads();
        const float* pr = pooled + (size_t)b * (HOP_ * D_) + p0;
#pragma unroll 4
        for (int i = 0; i < 1024; i += 4) {
            float4 wv = *(const float4*)&w[jj][i];
            float4 pv = *(const float4*)&pr[i];
            acc += wv.x * pv.x + wv.y * pv.y + wv.z * pv.z + wv.w * pv.w;
        }
    }
    out[(size_t)b * D_ + j0 + jj] = acc + fcb[j0 + jj];
}

extern "C" void kernel_launch(void* const* d_in, const int* in_sizes, int n_in,
                              void* d_out, int out_size, void* d_ws, size_t ws_size,
                              hipStream_t stream) {
    const float* input = (const float*)d_in[0];
    const float* W0   = (const float*)d_in[2];
    const float* b0   = (const float*)d_in[3];
    const float* W1   = (const float*)d_in[4];
    const float* b1   = (const float*)d_in[5];
    const float* ws1  = (const float*)d_in[6];
    const float* ws2  = (const float*)d_in[7];
    const float* fc_w = (const float*)d_in[8];
    const float* fc_b = (const float*)d_in[9];

    float* out  = (float*)d_out;
    float* attn = out + (size_t)B_ * D_;
    (void)in_sizes; (void)n_in; (void)out_size;

    const int M = B_ * T_;
    char* ws = (char*)d_ws;

    // ---- fast path: needs ~349 MB ----
    const size_t NEED2 = 348913792ull;
    const size_t NEED1 = 100663424ull;

    if (ws_size >= NEED2) {
        unsigned short* xinb = (unsigned short*)(ws);                // 33,554,432
        float*          x1f  = (float*)(ws + 33554432);              // 67,108,864
        unsigned short* x1b  = (unsigned short*)(ws + 100663296);    // 33,554,432
        float*          x2f  = (float*)(ws + 134217728);             // 67,108,864
        unsigned short* x2b  = (unsigned short*)(ws + 201326592);    // 33,554,432
        unsigned short* W0p  = (unsigned short*)(ws + 234881024);    // 6,291,456
        unsigned short* W1p  = (unsigned short*)(ws + 241172480);    // 6,291,456
        unsigned short* ws1p = (unsigned short*)(ws + 247463936);    // 786,432
        unsigned short* Up   = (unsigned short*)(ws + 248250368);    // 100,663,296
        int*            len  = (int*)(ws + 348913664);
        // alias dead U' region after scan2:
        float* hbar   = (float*)(ws + 248250368);
        float* alph   = (float*)(ws + 248250368 + 22937600);
        float* pooled = (float*)(ws + 248250368 + 23461888);

        lengths_k<<<B_, 512, 0, stream>>>(input, len);
        convX_k<<<(M * D_ / 4) / 256, 256, 0, stream>>>(input, xinb);
        convW_k<false><<<(D_ * 3 * D_) / 256, 256, 0, stream>>>(W0, W0p, D_, 3 * D_, 24, 3 * D_);
        convW_k<false><<<(D_ * 3 * D_) / 256, 256, 0, stream>>>(W1, W1p, D_, 3 * D_, 24, 3 * D_);
        convW_k<true><<<(D_ * 384) / 256, 256, 0, stream>>>(ws1, ws1p, D_, 384, 3, HID_);

        // Layer 1
        gemm_mfma<0><<<dim3(24, M / 128), 256, 0, stream>>>(xinb, W0p, b0, Up, D_, 24, 0);
        sru_scan_bf<<<(B_ * D_) / 64, 64, 0, stream>>>(Up, input, x1f, x1b);
        // Layer 2
        gemm_mfma<0><<<dim3(24, M / 128), 256, 0, stream>>>(x1b, W1p, b1, Up, D_, 24, 0);
        sru_scan_bf<<<(B_ * D_) / 64, 64, 0, stream>>>(Up, x1f, x2f, x2b);
        // hbar = tanh(x2 @ ws1^T)
        gemm_mfma<1><<<dim3(3, M / 128), 256, 0, stream>>>(x2b, ws1p, nullptr, hbar, D_, 3, HID_);

        alphas_k<<<M / 256, 256, 0, stream>>>(hbar, ws2, alph);
        softmax_k<<<B_ * HOP_, 256, 0, stream>>>(alph, len, attn);
        pooled_k<<<B_ * 4, 256, 0, stream>>>(attn, x2f, pooled);
        fc_k<<<D_ / 8, 256, 0, stream>>>(pooled, fc_w, fc_b, out);
        return;
    }

    // ---- fallback: chunked fp32 (round-2 proven) ----
    if (ws_size < NEED1) return;

    float* U    = (float*)ws;
    float* x1c  = (float*)(ws + 25165824);
    float* x2   = (float*)(ws + 33554432);
    int*   len  = (int*)(ws + 100663296);
    float* hbar   = (float*)ws;
    float* alph   = (float*)(ws + 22937600);
    float* pooled = (float*)(ws + 23461888);

    lengths_k<<<B_, 512, 0, stream>>>(input, len);

    const int Mc = CH_ * T_;
    for (int c0 = 0; c0 < B_; c0 += CH_) {
        const float* inC = input + (size_t)c0 * T_ * D_;
        float* x2C = x2 + (size_t)c0 * T_ * D_;
        gemm64<false, false><<<dim3(3 * D_ / 64, Mc / 64), 256, 0, stream>>>(
            inC, W0, U, Mc, 3 * D_, D_);
        sru_scan<<<CH_ * D_ / 256, 256, 0, stream>>>(U, b0, inC, x1c);
        gemm64<false, false><<<dim3(3 * D_ / 64, Mc / 64), 256, 0, stream>>>(
            x1c, W1, U, Mc, 3 * D_, D_);
        sru_scan<<<CH_ * D_ / 256, 256, 0, stream>>>(U, b1, x1c, x2C);
    }

    gemm64<true, true><<<dim3((HID_ + 63) / 64, M / 64), 256, 0, stream>>>(
        x2, ws1, hbar, M, HID_, D_);
    alphas_k<<<M / 256, 256, 0, stream>>>(hbar, ws2, alph);
    softmax_k<<<B_ * HOP_, 256, 0, stream>>>(alph, len, attn);
    pooled_k<<<B_ * 4, 256, 0, stream>>>(attn, x2, pooled);
    fc_k<<<D_ / 8, 256, 0, stream>>>(pooled, fc_w, fc_b, out);
}

// Round 4
// 825.598 us; speedup vs baseline: 6.1212x; 6.0417x over previous
//
#include <hip/hip_runtime.h>
#include <hip/hip_bf16.h>

#define B_ 32
#define T_ 512
#define D_ 1024
#define HOP_ 8
#define HID_ 350
#define NEGV -1e30f
#define CH_ 4  // batches per chunk (fp32 fallback path)

typedef __bf16 v8bf __attribute__((ext_vector_type(8)));
typedef float  v4f  __attribute__((ext_vector_type(4)));

__device__ __forceinline__ float fast_sigmoid(float x) {
    return 1.0f / (1.0f + __expf(-x));
}
__device__ __forceinline__ float fast_tanh(float x) {
    return 1.0f - 2.0f / (__expf(2.0f * x) + 1.0f);
}
__device__ __forceinline__ float bf2f(unsigned short u) {
    unsigned x = ((unsigned)u) << 16;
    float f;
    __builtin_memcpy(&f, &x, 4);
    return f;
}
__device__ __forceinline__ unsigned short f2bf(float v) {
    __hip_bfloat16 h = __float2bfloat16(v);
    unsigned short u;
    __builtin_memcpy(&u, &h, 2);
    return u;
}

// ---------------- lengths ----------------
__global__ __launch_bounds__(512) void lengths_k(const float* __restrict__ input,
                                                 int* __restrict__ len) {
    int b = blockIdx.x;
    int t = threadIdx.x;
    int z = (input[((size_t)b * T_ + t) * D_] == 0.0f) ? 1 : 0;
    __shared__ int cnt;
    if (t == 0) cnt = 0;
    __syncthreads();
    unsigned long long m = __ballot(z);
    if ((t & 63) == 0) atomicAdd(&cnt, __popcll(m));
    __syncthreads();
    if (t == 0) len[b] = T_ - cnt;
}

// =================== FAST PATH (bf16 MFMA) ===================

// fp32 -> bf16 rowmajor copy (vector 4)
__global__ __launch_bounds__(256) void convX_k(const float* __restrict__ in,
                                               unsigned short* __restrict__ out) {
    int i = (blockIdx.x * 256 + threadIdx.x) * 4;
    float4 v = *(const float4*)&in[i];
    out[i + 0] = f2bf(v.x);
    out[i + 1] = f2bf(v.y);
    out[i + 2] = f2bf(v.z);
    out[i + 3] = f2bf(v.w);
}

// weight -> tiled bf16 layout [kb][nb][n:128][k:32]  (4096 elems per tile)
// NT=false: W is (K,N) row-major. NT=true: W is (Nreal,K) row-major, zero-pad n>=Nreal.
template <bool NT>
__global__ __launch_bounds__(256) void convW_k(const float* __restrict__ W,
                                               unsigned short* __restrict__ Wp,
                                               int K, int N, int nT, int Nreal) {
    int o = blockIdx.x * 256 + threadIdx.x;
    int tile = o >> 12;          // 128*32 = 4096 elems per tile
    int within = o & 4095;
    int n_l = within >> 5, k_l = within & 31;
    int kb = tile / nT, nbb = tile % nT;
    int n = nbb * 128 + n_l, k = kb * 32 + k_l;
    float v = 0.f;
    if (NT) {
        if (n < Nreal) v = W[(size_t)n * K + k];
    } else {
        v = W[(size_t)k * N + n];
    }
    Wp[o] = f2bf(v);
}

// MFMA GEMM: C = A(M,K) @ B(K,N), 128x128 tile, BK=32, 4 waves of 64x64.
// EPI 0: SRU epilogue -> bf16 U' (stride 3072), sigmoid+bias for cols >= 1024.
// EPI 1: tanh epilogue -> fp32 C (stride Nstore), guard col < Nstore.
template <int EPI>
__global__ __launch_bounds__(256) void gemm_mfma(
    const unsigned short* __restrict__ A,
    const unsigned short* __restrict__ Bp,
    const float* __restrict__ bias,
    void* __restrict__ C,
    int K, int nT, int Nstore) {
    __shared__ __align__(16) unsigned short As[128 * 32];
    __shared__ __align__(16) unsigned short Bs[128 * 32];
    const int tid = threadIdx.x;
    const int lane = tid & 63;
    const int wid = __builtin_amdgcn_readfirstlane(tid >> 6);
    const int wm = wid & 1, wn = wid >> 1;
    const int m0 = blockIdx.y * 128;
    const int n0 = blockIdx.x * 128;
    const int nb = blockIdx.x;
    const int quad = lane >> 4;
    const int l15 = lane & 15;

    v4f acc[4][4];
#pragma unroll
    for (int i = 0; i < 4; ++i)
#pragma unroll
        for (int j = 0; j < 4; ++j) acc[i][j] = (v4f)(0.f);

    const int nKB = K >> 5;
    for (int kb = 0; kb < nKB; ++kb) {
        __syncthreads();
        // stage A: 128 rows x 32 k; granule g (16B) -> row g>>2, kpart g&3
#pragma unroll
        for (int p = 0; p < 2; ++p) {
            int g = p * 256 + wid * 64 + lane;
            const unsigned short* gp = A + (size_t)(m0 + (g >> 2)) * K + kb * 32 + (g & 3) * 8;
            int ldsOff = (p * 256 + wid * 64) * 16;
            __builtin_amdgcn_global_load_lds(
                (const __attribute__((address_space(1))) void*)gp,
                (__attribute__((address_space(3))) void*)((char*)As + ldsOff),
                16, 0, 0);
        }
        // stage B: linear copy of pre-tiled 8KB block
        const unsigned short* bt = Bp + (size_t)(kb * nT + nb) * (128 * 32);
#pragma unroll
        for (int p = 0; p < 2; ++p) {
            int g = p * 256 + wid * 64 + lane;
            const unsigned short* gp = bt + g * 8;
            int ldsOff = (p * 256 + wid * 64) * 16;
            __builtin_amdgcn_global_load_lds(
                (const __attribute__((address_space(1))) void*)gp,
                (__attribute__((address_space(3))) void*)((char*)Bs + ldsOff),
                16, 0, 0);
        }
        __syncthreads();
        v8bf af[4], bfr[4];
#pragma unroll
        for (int mi = 0; mi < 4; ++mi)
            af[mi] = *(const v8bf*)&As[(wm * 64 + mi * 16 + l15) * 32 + quad * 8];
#pragma unroll
        for (int ni = 0; ni < 4; ++ni)
            bfr[ni] = *(const v8bf*)&Bs[(wn * 64 + ni * 16 + l15) * 32 + quad * 8];
#pragma unroll
        for (int mi = 0; mi < 4; ++mi)
#pragma unroll
            for (int ni = 0; ni < 4; ++ni)
                acc[mi][ni] = __builtin_amdgcn_mfma_f32_16x16x32_bf16(
                    af[mi], bfr[ni], acc[mi][ni], 0, 0, 0);
    }

    const int baseM = m0 + wm * 64;
    const int baseN = n0 + wn * 64;
    if (EPI == 0) {
        unsigned short* Up = (unsigned short*)C;
#pragma unroll
        for (int ni = 0; ni < 4; ++ni) {
            int j = baseN + ni * 16 + l15;
            bool sig = j >= 1024;
            float bv = sig ? bias[j - 1024] : 0.f;  // works for f and r ranges
#pragma unroll
            for (int mi = 0; mi < 4; ++mi) {
                int m = baseM + mi * 16 + quad * 4;
                v4f c = acc[mi][ni];
#pragma unroll
                for (int r = 0; r < 4; ++r) {
                    float v = c[r];
                    if (sig) v = fast_sigmoid(v + bv);
                    Up[(size_t)(m + r) * 3072 + j] = f2bf(v);
                }
            }
        }
    } else {
        float* Cf = (float*)C;
#pragma unroll
        for (int ni = 0; ni < 4; ++ni) {
            int j = baseN + ni * 16 + l15;
            if (j < Nstore) {
#pragma unroll
                for (int mi = 0; mi < 4; ++mi) {
                    int m = baseM + mi * 16 + quad * 4;
                    v4f c = acc[mi][ni];
#pragma unroll
                    for (int r = 0; r < 4; ++r)
                        Cf[(size_t)(m + r) * Nstore + j] = fast_tanh(c[r]);
                }
            }
        }
    }
}

// SRU scan over bf16 U' = {xt, f=sigmoid'd, r=sigmoid'd}; bf16 residual or fp32.
// Double-buffered group-of-8 prefetch; writes bf16 x_out only.
#define LOADG(T0, XT, F, R, XV)                                          \
    _Pragma("unroll") for (int j = 0; j < 8; ++j) {                      \
        const unsigned short* u = Ub + (size_t)((T0) + j) * 3072;        \
        XT[j] = bf2f(u[0]);                                              \
        F[j] = bf2f(u[1024]);                                            \
        R[j] = bf2f(u[2048]);                                            \
        XV[j] = RESF32 ? xrf[(size_t)((T0) + j) * D_]                    \
                       : bf2f(xrb[(size_t)((T0) + j) * D_]);             \
    }
#define STEP8(T0, XT, F, R, XV)                                          \
    _Pragma("unroll") for (int j = 0; j < 8; ++j) {                      \
        c = F[j] * c + (1.f - F[j]) * XT[j];                             \
        float o = R[j] * fast_tanh(c) + (1.f - R[j]) * XV[j];            \
        ob[(size_t)((T0) + j) * D_] = f2bf(o);                           \
    }

template <bool RESF32>
__global__ __launch_bounds__(64) void sru_scan_bf(const unsigned short* __restrict__ Up,
                                                  const float* __restrict__ xresf,
                                                  const unsigned short* __restrict__ xresb,
                                                  unsigned short* __restrict__ xoutb) {
    int idx = blockIdx.x * 64 + threadIdx.x;  // (local b)*D + d
    int b = idx >> 10, d = idx & (D_ - 1);
    const unsigned short* Ub = Up + (size_t)b * T_ * 3072 + d;
    const float* xrf = RESF32 ? (xresf + (size_t)b * T_ * D_ + d) : nullptr;
    const unsigned short* xrb = RESF32 ? nullptr : (xresb + (size_t)b * T_ * D_ + d);
    unsigned short* ob = xoutb + (size_t)b * T_ * D_ + d;
    float c = 0.f;
    float axt[8], afv[8], arv[8], axv[8];
    float bxt[8], bfv[8], brv[8], bxv[8];
    LOADG(0, axt, afv, arv, axv);
    for (int t0 = 0; t0 < T_; t0 += 16) {
        LOADG(t0 + 8, bxt, bfv, brv, bxv);
        STEP8(t0, axt, afv, arv, axv);
        if (t0 + 16 < T_) { LOADG(t0 + 16, axt, afv, arv, axv); }
        STEP8(t0 + 8, bxt, bfv, brv, bxv);
    }
}

// =================== FALLBACK PATH (fp32, chunked; round-2 proven) ===================

template <bool BT, bool DO_TANH>
__global__ __launch_bounds__(256) void gemm64(const float* __restrict__ A,
                                              const float* __restrict__ Bm,
                                              float* __restrict__ C,
                                              int M, int N, int K) {
    __shared__ float Asm[16][64];
    __shared__ float Bsm[16][64];
    const int tid = threadIdx.x;
    const int tx = tid & 15;
    const int ty = tid >> 4;
    const int m0 = blockIdx.y * 64;
    const int n0 = blockIdx.x * 64;
    float acc[4][4] = {};
    const int ar = tid >> 2;
    const int ac = (tid & 3) << 2;

    for (int k0 = 0; k0 < K; k0 += 16) {
        {
            float4 v = *(const float4*)&A[(size_t)(m0 + ar) * K + k0 + ac];
            Asm[ac + 0][ar] = v.x; Asm[ac + 1][ar] = v.y;
            Asm[ac + 2][ar] = v.z; Asm[ac + 3][ar] = v.w;
        }
        if (!BT) {
            int kk = tid >> 4;
            int c4 = (tid & 15) << 2;
            float4 v = *(const float4*)&Bm[(size_t)(k0 + kk) * N + n0 + c4];
            Bsm[kk][c4 + 0] = v.x; Bsm[kk][c4 + 1] = v.y;
            Bsm[kk][c4 + 2] = v.z; Bsm[kk][c4 + 3] = v.w;
        } else {
            int nn = tid >> 2;
            int kk = (tid & 3) << 2;
            int row = n0 + nn;
            if (row < N) {
                float4 v = *(const float4*)&Bm[(size_t)row * K + k0 + kk];
                Bsm[kk + 0][nn] = v.x; Bsm[kk + 1][nn] = v.y;
                Bsm[kk + 2][nn] = v.z; Bsm[kk + 3][nn] = v.w;
            } else {
                Bsm[kk + 0][nn] = 0.f; Bsm[kk + 1][nn] = 0.f;
                Bsm[kk + 2][nn] = 0.f; Bsm[kk + 3][nn] = 0.f;
            }
        }
        __syncthreads();
#pragma unroll
        for (int kk = 0; kk < 16; ++kk) {
            float4 a = *(const float4*)&Asm[kk][ty << 2];
            float4 b = *(const float4*)&Bsm[kk][tx << 2];
            float am[4] = {a.x, a.y, a.z, a.w};
            float bm[4] = {b.x, b.y, b.z, b.w};
#pragma unroll
            for (int i = 0; i < 4; ++i)
#pragma unroll
                for (int j = 0; j < 4; ++j)
                    acc[i][j] += am[i] * bm[j];
        }
        __syncthreads();
    }
#pragma unroll
    for (int i = 0; i < 4; ++i) {
        int row = m0 + (ty << 2) + i;
#pragma unroll
        for (int j = 0; j < 4; ++j) {
            int col = n0 + (tx << 2) + j;
            if (col < N) {
                float v = acc[i][j];
                if (DO_TANH) v = fast_tanh(v);
                C[(size_t)row * N + col] = v;
            }
        }
    }
}

__global__ __launch_bounds__(256) void sru_scan(const float* __restrict__ U,
                                                const float* __restrict__ bias,
                                                const float* __restrict__ xin,
                                                float* __restrict__ xout) {
    int idx = blockIdx.x * 256 + threadIdx.x;
    int b = idx >> 10;
    int d = idx & (D_ - 1);
    float bfv = bias[d], br = bias[D_ + d];
    float c = 0.0f;
    const float* Ub = U + (size_t)b * T_ * (3 * D_);
    const float* xb = xin + (size_t)b * T_ * D_;
    float* ob = xout + (size_t)b * T_ * D_;
    for (int t = 0; t < T_; t += 8) {
        float ux[8], uf[8], ur[8], xv[8];
#pragma unroll
        for (int j = 0; j < 8; ++j) {
            const float* u = Ub + (size_t)(t + j) * (3 * D_);
            ux[j] = u[d];
            uf[j] = u[D_ + d];
            ur[j] = u[2 * D_ + d];
            xv[j] = xb[(size_t)(t + j) * D_ + d];
        }
#pragma unroll
        for (int j = 0; j < 8; ++j) {
            float f = fast_sigmoid(uf[j] + bfv);
            float r = fast_sigmoid(ur[j] + br);
            c = f * c + (1.0f - f) * ux[j];
            ob[(size_t)(t + j) * D_ + d] = r * fast_tanh(c) + (1.0f - r) * xv[j];
        }
    }
}

// =================== shared tail kernels ===================

__global__ __launch_bounds__(256) void alphas_k(const float* __restrict__ hbar,
                                                const float* __restrict__ ws2,
                                                float* __restrict__ alph) {
    __shared__ float w[HOP_][352];
    for (int i = threadIdx.x; i < HOP_ * HID_; i += 256)
        w[i / HID_][i % HID_] = ws2[i];
    __syncthreads();
    int bt = blockIdx.x * 256 + threadIdx.x;
    const float* hr = hbar + (size_t)bt * HID_;
    float acc[HOP_] = {};
    for (int h = 0; h < HID_; ++h) {
        float hv = hr[h];
#pragma unroll
        for (int k = 0; k < HOP_; ++k) acc[k] += w[k][h] * hv;
    }
    float* ar = alph + (size_t)bt * HOP_;
#pragma unroll
    for (int k = 0; k < HOP_; ++k) ar[k] = acc[k];
}

__global__ __launch_bounds__(256) void softmax_k(const float* __restrict__ alph,
                                                 const int* __restrict__ len,
                                                 float* __restrict__ attn) {
    int b = blockIdx.x >> 3, k = blockIdx.x & 7;
    int L = len[b];
    int t0 = threadIdx.x, t1 = threadIdx.x + 256;
    float v0 = (t0 >= L) ? NEGV : alph[((size_t)b * T_ + t0) * HOP_ + k];
    float v1 = (t1 >= L) ? NEGV : alph[((size_t)b * T_ + t1) * HOP_ + k];
    __shared__ float redm[4];
    __shared__ float reds[4];
    float m = fmaxf(v0, v1);
#pragma unroll
    for (int off = 32; off; off >>= 1) m = fmaxf(m, __shfl_xor(m, off));
    if ((threadIdx.x & 63) == 0) redm[threadIdx.x >> 6] = m;
    __syncthreads();
    m = fmaxf(fmaxf(redm[0], redm[1]), fmaxf(redm[2], redm[3]));
    float e0 = __expf(v0 - m), e1 = __expf(v1 - m);
    float s = e0 + e1;
#pragma unroll
    for (int off = 32; off; off >>= 1) s += __shfl_xor(s, off);
    if ((threadIdx.x & 63) == 0) reds[threadIdx.x >> 6] = s;
    __syncthreads();
    s = reds[0] + reds[1] + reds[2] + reds[3];
    float inv = 1.0f / s;
    float* ar = attn + ((size_t)b * HOP_ + k) * T_;
    ar[t0] = e0 * inv;
    ar[t1] = e1 * inv;
}

// pooled from bf16 x2
__global__ __launch_bounds__(256) void pooled_bf_k(const float* __restrict__ attn,
                                                   const unsigned short* __restrict__ x2b,
                                                   float* __restrict__ pooled) {
    __shared__ float at[HOP_][T_];
    int b = blockIdx.x >> 2;
    int d0 = (blockIdx.x & 3) * 256;
    for (int i = threadIdx.x; i < HOP_ * T_; i += 256)
        at[i >> 9][i & (T_ - 1)] = attn[(size_t)b * HOP_ * T_ + i];
    __syncthreads();
    int d = d0 + threadIdx.x;
    float acc[HOP_] = {};
    const unsigned short* xb = x2b + (size_t)b * T_ * D_ + d;
    for (int t = 0; t < T_; ++t) {
        float xv = bf2f(xb[(size_t)t * D_]);
#pragma unroll
        for (int k = 0; k < HOP_; ++k) acc[k] += at[k][t] * xv;
    }
#pragma unroll
    for (int k = 0; k < HOP_; ++k)
        pooled[((size_t)b * HOP_ + k) * D_ + d] = acc[k];
}

// pooled from fp32 x2 (fallback)
__global__ __launch_bounds__(256) void pooled_k(const float* __restrict__ attn,
                                                const float* __restrict__ x2,
                                                float* __restrict__ pooled) {
    __shared__ float at[HOP_][T_];
    int b = blockIdx.x >> 2;
    int d0 = (blockIdx.x & 3) * 256;
    for (int i = threadIdx.x; i < HOP_ * T_; i += 256)
        at[i >> 9][i & (T_ - 1)] = attn[(size_t)b * HOP_ * T_ + i];
    __syncthreads();
    int d = d0 + threadIdx.x;
    float acc[HOP_] = {};
    const float* xb = x2 + (size_t)b * T_ * D_ + d;
    for (int t = 0; t < T_; ++t) {
        float xv = xb[(size_t)t * D_];
#pragma unroll
        for (int k = 0; k < HOP_; ++k) acc[k] += at[k][t] * xv;
    }
#pragma unroll
    for (int k = 0; k < HOP_; ++k)
        pooled[((size_t)b * HOP_ + k) * D_ + d] = acc[k];
}

__global__ __launch_bounds__(256) void fc_k(const float* __restrict__ pooled,
                                            const float* __restrict__ fcw,
                                            const float* __restrict__ fcb,
                                            float* __restrict__ out) {
    __shared__ float w[8][1028];
    int j0 = blockIdx.x * 8;
    int b = threadIdx.x >> 3, jj = threadIdx.x & 7;
    float acc = 0.0f;
    for (int p0 = 0; p0 < HOP_ * D_; p0 += 1024) {
        __syncthreads();
        for (int i = threadIdx.x * 4; i < 8 * 1024; i += 256 * 4) {
            int r = i >> 10, c = i & 1023;
            *(float4*)&w[r][c] = *(const float4*)&fcw[(size_t)(j0 + r) * (HOP_ * D_) + p0 + c];
        }
        __syncthreads();
        const float* pr = pooled + (size_t)b * (HOP_ * D_) + p0;
#pragma unroll 4
        for (int i = 0; i < 1024; i += 4) {
            float4 wv = *(const float4*)&w[jj][i];
            float4 pv = *(const float4*)&pr[i];
            acc += wv.x * pv.x + wv.y * pv.y + wv.z * pv.z + wv.w * pv.w;
        }
    }
    out[(size_t)b * D_ + j0 + jj] = acc + fcb[j0 + jj];
}

extern "C" void kernel_launch(void* const* d_in, const int* in_sizes, int n_in,
                              void* d_out, int out_size, void* d_ws, size_t ws_size,
                              hipStream_t stream) {
    const float* input = (const float*)d_in[0];
    const float* W0   = (const float*)d_in[2];
    const float* b0   = (const float*)d_in[3];
    const float* W1   = (const float*)d_in[4];
    const float* b1   = (const float*)d_in[5];
    const float* ws1  = (const float*)d_in[6];
    const float* ws2  = (const float*)d_in[7];
    const float* fc_w = (const float*)d_in[8];
    const float* fc_b = (const float*)d_in[9];

    float* out  = (float*)d_out;
    float* attn = out + (size_t)B_ * D_;
    (void)in_sizes; (void)n_in; (void)out_size;

    const int M = B_ * T_;
    char* ws = (char*)d_ws;

    // Tier A (unchunked): 181,141,632 B.  Tier B (CH=8): 80,478,336 B.
    const size_t NEED_A = 181141632ull;
    const size_t NEED_B = 80478336ull;
    const size_t NEED_FB = 100663424ull;

    if (ws_size >= NEED_B) {
        const int CHv = (ws_size >= NEED_A) ? 32 : 8;
        const size_t szU = (size_t)CHv * 512 * 3072 * 2;
        const size_t szX = (size_t)CHv * 512 * 1024 * 2;
        unsigned short* Uc   = (unsigned short*)ws;
        unsigned short* xbc  = (unsigned short*)(ws + szU);
        unsigned short* x2b  = (unsigned short*)(ws + szU + szX);
        unsigned short* W0p  = (unsigned short*)(ws + szU + szX + 33554432);
        unsigned short* W1p  = W0p + 3145728;
        unsigned short* ws1p = W1p + 3145728;
        int*            len  = (int*)(ws1p + 393216);
        // alias dead U' region after the chunk loop:
        float* hbar   = (float*)ws;                    // 22,937,600
        float* alph   = (float*)(ws + 22937600);       // 524,288
        float* pooled = (float*)(ws + 23461888);       // 1,048,576 (<= 25,165,824) OK

        lengths_k<<<B_, 512, 0, stream>>>(input, len);
        convW_k<false><<<(D_ * 3 * D_) / 256, 256, 0, stream>>>(W0, W0p, D_, 3 * D_, 24, 3 * D_);
        convW_k<false><<<(D_ * 3 * D_) / 256, 256, 0, stream>>>(W1, W1p, D_, 3 * D_, 24, 3 * D_);
        convW_k<true><<<(D_ * 384) / 256, 256, 0, stream>>>(ws1, ws1p, D_, 384, 3, HID_);

        for (int c0 = 0; c0 < B_; c0 += CHv) {
            const float* inC = input + (size_t)c0 * T_ * D_;
            const int Mc = CHv * T_;
            convX_k<<<(Mc * D_ / 4) / 256, 256, 0, stream>>>(inC, xbc);
            // Layer 1
            gemm_mfma<0><<<dim3(24, Mc / 128), 256, 0, stream>>>(xbc, W0p, b0, Uc, D_, 24, 0);
            sru_scan_bf<true><<<CHv * D_ / 64, 64, 0, stream>>>(Uc, inC, nullptr, xbc);
            // Layer 2
            gemm_mfma<0><<<dim3(24, Mc / 128), 256, 0, stream>>>(xbc, W1p, b1, Uc, D_, 24, 0);
            sru_scan_bf<false><<<CHv * D_ / 64, 64, 0, stream>>>(
                Uc, nullptr, xbc, x2b + (size_t)c0 * T_ * D_);
        }

        // hbar = tanh(x2 @ ws1^T) over full M (U' region now dead -> hbar)
        gemm_mfma<1><<<dim3(3, M / 128), 256, 0, stream>>>(x2b, ws1p, nullptr, hbar, D_, 3, HID_);

        alphas_k<<<M / 256, 256, 0, stream>>>(hbar, ws2, alph);
        softmax_k<<<B_ * HOP_, 256, 0, stream>>>(alph, len, attn);
        pooled_bf_k<<<B_ * 4, 256, 0, stream>>>(attn, x2b, pooled);
        fc_k<<<D_ / 8, 256, 0, stream>>>(pooled, fc_w, fc_b, out);
        return;
    }

    // ---- fallback: chunked fp32 (round-2 proven) ----
    if (ws_size < NEED_FB) return;

    float* U    = (float*)ws;
    float* x1c  = (float*)(ws + 25165824);
    float* x2   = (float*)(ws + 33554432);
    int*   len  = (int*)(ws + 100663296);
    float* hbar   = (float*)ws;
    float* alph   = (float*)(ws + 22937600);
    float* pooled = (float*)(ws + 23461888);

    lengths_k<<<B_, 512, 0, stream>>>(input, len);

    const int Mc = CH_ * T_;
    for (int c0 = 0; c0 < B_; c0 += CH_) {
        const float* inC = input + (size_t)c0 * T_ * D_;
        float* x2C = x2 + (size_t)c0 * T_ * D_;
        gemm64<false, false><<<dim3(3 * D_ / 64, Mc / 64), 256, 0, stream>>>(
            inC, W0, U, Mc, 3 * D_, D_);
        sru_scan<<<CH_ * D_ / 256, 256, 0, stream>>>(U, b0, inC, x1c);
        gemm64<false, false><<<dim3(3 * D_ / 64, Mc / 64), 256, 0, stream>>>(
            x1c, W1, U, Mc, 3 * D_, D_);
        sru_scan<<<CH_ * D_ / 256, 256, 0, stream>>>(U, b1, x1c, x2C);
    }

    gemm64<true, true><<<dim3((HID_ + 63) / 64, M / 64), 256, 0, stream>>>(
        x2, ws1, hbar, M, HID_, D_);
    alphas_k<<<M / 256, 256, 0, stream>>>(hbar, ws2, alph);
    softmax_k<<<B_ * HOP_, 256, 0, stream>>>(alph, len, attn);
    pooled_k<<<B_ * 4, 256, 0, stream>>>(attn, x2, pooled);
    fc_k<<<D_ / 8, 256, 0, stream>>>(pooled, fc_w, fc_b, out);
}

// Round 5
// 781.577 us; speedup vs baseline: 6.4659x; 1.0563x over previous
//
#include <hip/hip_runtime.h>
#include <hip/hip_bf16.h>

#define B_ 32
#define T_ 512
#define D_ 1024
#define HOP_ 8
#define HID_ 350
#define NEGV -1e30f
#define CH_ 4  // batches per chunk (fp32 fallback path)

typedef __bf16 v8bf __attribute__((ext_vector_type(8)));
typedef float  v4f  __attribute__((ext_vector_type(4)));

__device__ __forceinline__ float fast_sigmoid(float x) {
    return 1.0f / (1.0f + __expf(-x));
}
__device__ __forceinline__ float fast_tanh(float x) {
    return 1.0f - 2.0f / (__expf(2.0f * x) + 1.0f);
}
__device__ __forceinline__ float bf2f(unsigned short u) {
    unsigned x = ((unsigned)u) << 16;
    float f;
    __builtin_memcpy(&f, &x, 4);
    return f;
}
__device__ __forceinline__ unsigned short f2bf(float v) {
    __hip_bfloat16 h = __float2bfloat16(v);
    unsigned short u;
    __builtin_memcpy(&u, &h, 2);
    return u;
}

// ---------------- lengths ----------------
__global__ __launch_bounds__(512) void lengths_k(const float* __restrict__ input,
                                                 int* __restrict__ len) {
    int b = blockIdx.x;
    int t = threadIdx.x;
    int z = (input[((size_t)b * T_ + t) * D_] == 0.0f) ? 1 : 0;
    __shared__ int cnt;
    if (t == 0) cnt = 0;
    __syncthreads();
    unsigned long long m = __ballot(z);
    if ((t & 63) == 0) atomicAdd(&cnt, __popcll(m));
    __syncthreads();
    if (t == 0) len[b] = T_ - cnt;
}

// =================== FAST PATH (bf16 MFMA) ===================

// fp32 -> bf16 rowmajor copy (vector 4)
__global__ __launch_bounds__(256) void convX_k(const float* __restrict__ in,
                                               unsigned short* __restrict__ out) {
    int i = (blockIdx.x * 256 + threadIdx.x) * 4;
    float4 v = *(const float4*)&in[i];
    out[i + 0] = f2bf(v.x);
    out[i + 1] = f2bf(v.y);
    out[i + 2] = f2bf(v.z);
    out[i + 3] = f2bf(v.w);
}

// weight -> tiled bf16 layout [kb][nb][n:128][k:32]  (4096 elems per tile)
// NT=false: W is (K,N) row-major. NT=true: W is (Nreal,K) row-major, zero-pad n>=Nreal.
template <bool NT>
__global__ __launch_bounds__(256) void convW_k(const float* __restrict__ W,
                                               unsigned short* __restrict__ Wp,
                                               int K, int N, int nT, int Nreal) {
    int o = blockIdx.x * 256 + threadIdx.x;
    int tile = o >> 12;          // 128*32 = 4096 elems per tile
    int within = o & 4095;
    int n_l = within >> 5, k_l = within & 31;
    int kb = tile / nT, nbb = tile % nT;
    int n = nbb * 128 + n_l, k = kb * 32 + k_l;
    float v = 0.f;
    if (NT) {
        if (n < Nreal) v = W[(size_t)n * K + k];
    } else {
        v = W[(size_t)k * N + n];
    }
    Wp[o] = f2bf(v);
}

// MFMA GEMM: C = A(M,K) @ B(K,N), 128x128 tile, BK=32, 4 waves of 64x64.
// EPI 0: raw bf16 store of the 128x128 tile via LDS transpose -> U' (stride 3072).
// EPI 1: tanh epilogue -> fp32 C (stride Nstore), guard col < Nstore.
template <int EPI>
__global__ __launch_bounds__(256) void gemm_mfma(
    const unsigned short* __restrict__ A,
    const unsigned short* __restrict__ Bp,
    void* __restrict__ C,
    int K, int nT, int Nstore) {
    __shared__ __align__(16) char smem[34816];  // staging 16 KB / C-tile 34 KB
    unsigned short* As = (unsigned short*)smem;
    unsigned short* Bs = (unsigned short*)(smem + 8192);
    const int tid = threadIdx.x;
    const int lane = tid & 63;
    const int wid = __builtin_amdgcn_readfirstlane(tid >> 6);
    const int wm = wid & 1, wn = wid >> 1;
    const int m0 = blockIdx.y * 128;
    const int n0 = blockIdx.x * 128;
    const int nb = blockIdx.x;
    const int quad = lane >> 4;
    const int l15 = lane & 15;

    v4f acc[4][4];
#pragma unroll
    for (int i = 0; i < 4; ++i)
#pragma unroll
        for (int j = 0; j < 4; ++j) acc[i][j] = (v4f)(0.f);

    const int nKB = K >> 5;
    for (int kb = 0; kb < nKB; ++kb) {
        __syncthreads();
        // stage A: 128 rows x 32 k; granule g (16B) -> row g>>2, kpart g&3
#pragma unroll
        for (int p = 0; p < 2; ++p) {
            int g = p * 256 + wid * 64 + lane;
            const unsigned short* gp = A + (size_t)(m0 + (g >> 2)) * K + kb * 32 + (g & 3) * 8;
            int ldsOff = (p * 256 + wid * 64) * 16;
            __builtin_amdgcn_global_load_lds(
                (const __attribute__((address_space(1))) void*)gp,
                (__attribute__((address_space(3))) void*)((char*)As + ldsOff),
                16, 0, 0);
        }
        // stage B: linear copy of pre-tiled 8KB block
        const unsigned short* bt = Bp + (size_t)(kb * nT + nb) * (128 * 32);
#pragma unroll
        for (int p = 0; p < 2; ++p) {
            int g = p * 256 + wid * 64 + lane;
            const unsigned short* gp = bt + g * 8;
            int ldsOff = (p * 256 + wid * 64) * 16;
            __builtin_amdgcn_global_load_lds(
                (const __attribute__((address_space(1))) void*)gp,
                (__attribute__((address_space(3))) void*)((char*)Bs + ldsOff),
                16, 0, 0);
        }
        __syncthreads();
        v8bf af[4], bfr[4];
#pragma unroll
        for (int mi = 0; mi < 4; ++mi)
            af[mi] = *(const v8bf*)&As[(wm * 64 + mi * 16 + l15) * 32 + quad * 8];
#pragma unroll
        for (int ni = 0; ni < 4; ++ni)
            bfr[ni] = *(const v8bf*)&Bs[(wn * 64 + ni * 16 + l15) * 32 + quad * 8];
#pragma unroll
        for (int mi = 0; mi < 4; ++mi)
#pragma unroll
            for (int ni = 0; ni < 4; ++ni)
                acc[mi][ni] = __builtin_amdgcn_mfma_f32_16x16x32_bf16(
                    af[mi], bfr[ni], acc[mi][ni], 0, 0, 0);
    }

    if (EPI == 0) {
        // LDS transpose epilogue: Ct row-major [128][136] (pad 8 shorts)
        __syncthreads();
        unsigned short* Ct = (unsigned short*)smem;
#pragma unroll
        for (int ni = 0; ni < 4; ++ni) {
            int n_l = wn * 64 + ni * 16 + l15;
#pragma unroll
            for (int mi = 0; mi < 4; ++mi) {
                int m_l = wm * 64 + mi * 16 + quad * 4;
                v4f cc = acc[mi][ni];
#pragma unroll
                for (int r = 0; r < 4; ++r)
                    Ct[(m_l + r) * 136 + n_l] = f2bf(cc[r]);
            }
        }
        __syncthreads();
        int row = tid >> 1;
        int colH = (tid & 1) << 6;
        unsigned short* gdst = (unsigned short*)C + (size_t)(m0 + row) * 3072 + n0 + colH;
        const unsigned short* lsrc = Ct + row * 136 + colH;
#pragma unroll
        for (int i = 0; i < 8; ++i) {
            uint4 v = *(const uint4*)(lsrc + i * 8);
            *(uint4*)(gdst + i * 8) = v;
        }
    } else {
        const int baseM = m0 + wm * 64;
        const int baseN = n0 + wn * 64;
        float* Cf = (float*)C;
#pragma unroll
        for (int ni = 0; ni < 4; ++ni) {
            int j = baseN + ni * 16 + l15;
            if (j < Nstore) {
#pragma unroll
                for (int mi = 0; mi < 4; ++mi) {
                    int m = baseM + mi * 16 + quad * 4;
                    v4f c = acc[mi][ni];
#pragma unroll
                    for (int r = 0; r < 4; ++r)
                        Cf[(size_t)(m + r) * Nstore + j] = fast_tanh(c[r]);
                }
            }
        }
    }
}

// Segmented SRU scan (fused 3-phase). U' holds raw preactivations {xt, uf, ur}.
// Block: 512 threads = 64 d x 8 segments; grid = (#batches)*16 d-chunks.
__global__ __launch_bounds__(512) void sru_scan_seg(
    const unsigned short* __restrict__ Up,
    const float* __restrict__ bias,
    const unsigned short* __restrict__ xres,
    unsigned short* __restrict__ xout) {
    int b = blockIdx.x >> 4;
    int d0 = (blockIdx.x & 15) << 6;
    int dl = threadIdx.x & 63;
    int s = threadIdx.x >> 6;
    int d = d0 + dl;
    float bf = bias[d], br = bias[D_ + d];
    const unsigned short* Ub = Up + (size_t)b * T_ * 3072 + d;
    const int t0 = s * 64;

    // phase A: per-segment affine composition (a = prod f, b = scan from 0)
    float Aa = 1.f, Bv = 0.f;
    for (int tt = 0; tt < 64; tt += 8) {
        float xt[8], fv[8];
#pragma unroll
        for (int j = 0; j < 8; ++j) {
            const unsigned short* u = Ub + (size_t)(t0 + tt + j) * 3072;
            xt[j] = bf2f(u[0]);
            fv[j] = bf2f(u[1024]);
        }
#pragma unroll
        for (int j = 0; j < 8; ++j) {
            float f = fast_sigmoid(fv[j] + bf);
            Aa *= f;
            Bv = f * Bv + (1.f - f) * xt[j];
        }
    }
    __shared__ float Asm[8][64], Bsm[8][64], cinS[8][64];
    Asm[s][dl] = Aa;
    Bsm[s][dl] = Bv;
    __syncthreads();
    // phase B: compose 8 segment summaries
    if (threadIdx.x < 64) {
        float c = 0.f;
#pragma unroll
        for (int ss = 0; ss < 8; ++ss) {
            cinS[ss][threadIdx.x] = c;
            c = Asm[ss][threadIdx.x] * c + Bsm[ss][threadIdx.x];
        }
    }
    __syncthreads();
    // phase C: re-scan with correct initial state, emit outputs
    float c = cinS[s][dl];
    const unsigned short* xr = xres + (size_t)b * T_ * D_ + d;
    unsigned short* ob = xout + (size_t)b * T_ * D_ + d;
    for (int tt = 0; tt < 64; tt += 4) {
        float xt[4], fv[4], rv[4], xv[4];
#pragma unroll
        for (int j = 0; j < 4; ++j) {
            const unsigned short* u = Ub + (size_t)(t0 + tt + j) * 3072;
            xt[j] = bf2f(u[0]);
            fv[j] = bf2f(u[1024]);
            rv[j] = bf2f(u[2048]);
            xv[j] = bf2f(xr[(size_t)(t0 + tt + j) * D_]);
        }
#pragma unroll
        for (int j = 0; j < 4; ++j) {
            float f = fast_sigmoid(fv[j] + bf);
            float r = fast_sigmoid(rv[j] + br);
            c = f * c + (1.f - f) * xt[j];
            float o = r * fast_tanh(c) + (1.f - r) * xv[j];
            ob[(size_t)(t0 + tt + j) * D_] = f2bf(o);
        }
    }
}

// =================== FALLBACK PATH (fp32, chunked; round-2 proven) ===================

template <bool BT, bool DO_TANH>
__global__ __launch_bounds__(256) void gemm64(const float* __restrict__ A,
                                              const float* __restrict__ Bm,
                                              float* __restrict__ C,
                                              int M, int N, int K) {
    __shared__ float Asm[16][64];
    __shared__ float Bsm[16][64];
    const int tid = threadIdx.x;
    const int tx = tid & 15;
    const int ty = tid >> 4;
    const int m0 = blockIdx.y * 64;
    const int n0 = blockIdx.x * 64;
    float acc[4][4] = {};
    const int ar = tid >> 2;
    const int ac = (tid & 3) << 2;

    for (int k0 = 0; k0 < K; k0 += 16) {
        {
            float4 v = *(const float4*)&A[(size_t)(m0 + ar) * K + k0 + ac];
            Asm[ac + 0][ar] = v.x; Asm[ac + 1][ar] = v.y;
            Asm[ac + 2][ar] = v.z; Asm[ac + 3][ar] = v.w;
        }
        if (!BT) {
            int kk = tid >> 4;
            int c4 = (tid & 15) << 2;
            float4 v = *(const float4*)&Bm[(size_t)(k0 + kk) * N + n0 + c4];
            Bsm[kk][c4 + 0] = v.x; Bsm[kk][c4 + 1] = v.y;
            Bsm[kk][c4 + 2] = v.z; Bsm[kk][c4 + 3] = v.w;
        } else {
            int nn = tid >> 2;
            int kk = (tid & 3) << 2;
            int row = n0 + nn;
            if (row < N) {
                float4 v = *(const float4*)&Bm[(size_t)row * K + k0 + kk];
                Bsm[kk + 0][nn] = v.x; Bsm[kk + 1][nn] = v.y;
                Bsm[kk + 2][nn] = v.z; Bsm[kk + 3][nn] = v.w;
            } else {
                Bsm[kk + 0][nn] = 0.f; Bsm[kk + 1][nn] = 0.f;
                Bsm[kk + 2][nn] = 0.f; Bsm[kk + 3][nn] = 0.f;
            }
        }
        __syncthreads();
#pragma unroll
        for (int kk = 0; kk < 16; ++kk) {
            float4 a = *(const float4*)&Asm[kk][ty << 2];
            float4 b = *(const float4*)&Bsm[kk][tx << 2];
            float am[4] = {a.x, a.y, a.z, a.w};
            float bm[4] = {b.x, b.y, b.z, b.w};
#pragma unroll
            for (int i = 0; i < 4; ++i)
#pragma unroll
                for (int j = 0; j < 4; ++j)
                    acc[i][j] += am[i] * bm[j];
        }
        __syncthreads();
    }
#pragma unroll
    for (int i = 0; i < 4; ++i) {
        int row = m0 + (ty << 2) + i;
#pragma unroll
        for (int j = 0; j < 4; ++j) {
            int col = n0 + (tx << 2) + j;
            if (col < N) {
                float v = acc[i][j];
                if (DO_TANH) v = fast_tanh(v);
                C[(size_t)row * N + col] = v;
            }
        }
    }
}

__global__ __launch_bounds__(256) void sru_scan(const float* __restrict__ U,
                                                const float* __restrict__ bias,
                                                const float* __restrict__ xin,
                                                float* __restrict__ xout) {
    int idx = blockIdx.x * 256 + threadIdx.x;
    int b = idx >> 10;
    int d = idx & (D_ - 1);
    float bfv = bias[d], br = bias[D_ + d];
    float c = 0.0f;
    const float* Ub = U + (size_t)b * T_ * (3 * D_);
    const float* xb = xin + (size_t)b * T_ * D_;
    float* ob = xout + (size_t)b * T_ * D_;
    for (int t = 0; t < T_; t += 8) {
        float ux[8], uf[8], ur[8], xv[8];
#pragma unroll
        for (int j = 0; j < 8; ++j) {
            const float* u = Ub + (size_t)(t + j) * (3 * D_);
            ux[j] = u[d];
            uf[j] = u[D_ + d];
            ur[j] = u[2 * D_ + d];
            xv[j] = xb[(size_t)(t + j) * D_ + d];
        }
#pragma unroll
        for (int j = 0; j < 8; ++j) {
            float f = fast_sigmoid(uf[j] + bfv);
            float r = fast_sigmoid(ur[j] + br);
            c = f * c + (1.0f - f) * ux[j];
            ob[(size_t)(t + j) * D_ + d] = r * fast_tanh(c) + (1.0f - r) * xv[j];
        }
    }
}

// =================== shared tail kernels ===================

__global__ __launch_bounds__(256) void alphas_k(const float* __restrict__ hbar,
                                                const float* __restrict__ ws2,
                                                float* __restrict__ alph) {
    __shared__ float w[HOP_][352];
    for (int i = threadIdx.x; i < HOP_ * HID_; i += 256)
        w[i / HID_][i % HID_] = ws2[i];
    __syncthreads();
    int bt = blockIdx.x * 256 + threadIdx.x;
    const float* hr = hbar + (size_t)bt * HID_;
    float acc[HOP_] = {};
    for (int h = 0; h < HID_; ++h) {
        float hv = hr[h];
#pragma unroll
        for (int k = 0; k < HOP_; ++k) acc[k] += w[k][h] * hv;
    }
    float* ar = alph + (size_t)bt * HOP_;
#pragma unroll
    for (int k = 0; k < HOP_; ++k) ar[k] = acc[k];
}

__global__ __launch_bounds__(256) void softmax_k(const float* __restrict__ alph,
                                                 const int* __restrict__ len,
                                                 float* __restrict__ attn) {
    int b = blockIdx.x >> 3, k = blockIdx.x & 7;
    int L = len[b];
    int t0 = threadIdx.x, t1 = threadIdx.x + 256;
    float v0 = (t0 >= L) ? NEGV : alph[((size_t)b * T_ + t0) * HOP_ + k];
    float v1 = (t1 >= L) ? NEGV : alph[((size_t)b * T_ + t1) * HOP_ + k];
    __shared__ float redm[4];
    __shared__ float reds[4];
    float m = fmaxf(v0, v1);
#pragma unroll
    for (int off = 32; off; off >>= 1) m = fmaxf(m, __shfl_xor(m, off));
    if ((threadIdx.x & 63) == 0) redm[threadIdx.x >> 6] = m;
    __syncthreads();
    m = fmaxf(fmaxf(redm[0], redm[1]), fmaxf(redm[2], redm[3]));
    float e0 = __expf(v0 - m), e1 = __expf(v1 - m);
    float s = e0 + e1;
#pragma unroll
    for (int off = 32; off; off >>= 1) s += __shfl_xor(s, off);
    if ((threadIdx.x & 63) == 0) reds[threadIdx.x >> 6] = s;
    __syncthreads();
    s = reds[0] + reds[1] + reds[2] + reds[3];
    float inv = 1.0f / s;
    float* ar = attn + ((size_t)b * HOP_ + k) * T_;
    ar[t0] = e0 * inv;
    ar[t1] = e1 * inv;
}

// pooled from bf16 x2
__global__ __launch_bounds__(256) void pooled_bf_k(const float* __restrict__ attn,
                                                   const unsigned short* __restrict__ x2b,
                                                   float* __restrict__ pooled) {
    __shared__ float at[HOP_][T_];
    int b = blockIdx.x >> 2;
    int d0 = (blockIdx.x & 3) * 256;
    for (int i = threadIdx.x; i < HOP_ * T_; i += 256)
        at[i >> 9][i & (T_ - 1)] = attn[(size_t)b * HOP_ * T_ + i];
    __syncthreads();
    int d = d0 + threadIdx.x;
    float acc[HOP_] = {};
    const unsigned short* xb = x2b + (size_t)b * T_ * D_ + d;
    for (int t = 0; t < T_; ++t) {
        float xv = bf2f(xb[(size_t)t * D_]);
#pragma unroll
        for (int k = 0; k < HOP_; ++k) acc[k] += at[k][t] * xv;
    }
#pragma unroll
    for (int k = 0; k < HOP_; ++k)
        pooled[((size_t)b * HOP_ + k) * D_ + d] = acc[k];
}

// pooled from fp32 x2 (fallback)
__global__ __launch_bounds__(256) void pooled_k(const float* __restrict__ attn,
                                                const float* __restrict__ x2,
                                                float* __restrict__ pooled) {
    __shared__ float at[HOP_][T_];
    int b = blockIdx.x >> 2;
    int d0 = (blockIdx.x & 3) * 256;
    for (int i = threadIdx.x; i < HOP_ * T_; i += 256)
        at[i >> 9][i & (T_ - 1)] = attn[(size_t)b * HOP_ * T_ + i];
    __syncthreads();
    int d = d0 + threadIdx.x;
    float acc[HOP_] = {};
    const float* xb = x2 + (size_t)b * T_ * D_ + d;
    for (int t = 0; t < T_; ++t) {
        float xv = xb[(size_t)t * D_];
#pragma unroll
        for (int k = 0; k < HOP_; ++k) acc[k] += at[k][t] * xv;
    }
#pragma unroll
    for (int k = 0; k < HOP_; ++k)
        pooled[((size_t)b * HOP_ + k) * D_ + d] = acc[k];
}

__global__ __launch_bounds__(256) void fc_k(const float* __restrict__ pooled,
                                            const float* __restrict__ fcw,
                                            const float* __restrict__ fcb,
                                            float* __restrict__ out) {
    __shared__ float w[8][1028];
    int j0 = blockIdx.x * 8;
    int b = threadIdx.x >> 3, jj = threadIdx.x & 7;
    float acc = 0.0f;
    for (int p0 = 0; p0 < HOP_ * D_; p0 += 1024) {
        __syncthreads();
        for (int i = threadIdx.x * 4; i < 8 * 1024; i += 256 * 4) {
            int r = i >> 10, c = i & 1023;
            *(float4*)&w[r][c] = *(const float4*)&fcw[(size_t)(j0 + r) * (HOP_ * D_) + p0 + c];
        }
        __syncthreads();
        const float* pr = pooled + (size_t)b * (HOP_ * D_) + p0;
#pragma unroll 4
        for (int i = 0; i < 1024; i += 4) {
            float4 wv = *(const float4*)&w[jj][i];
            float4 pv = *(const float4*)&pr[i];
            acc += wv.x * pv.x + wv.y * pv.y + wv.z * pv.z + wv.w * pv.w;
        }
    }
    out[(size_t)b * D_ + j0 + jj] = acc + fcb[j0 + jj];
}

extern "C" void kernel_launch(void* const* d_in, const int* in_sizes, int n_in,
                              void* d_out, int out_size, void* d_ws, size_t ws_size,
                              hipStream_t stream) {
    const float* input = (const float*)d_in[0];
    const float* W0   = (const float*)d_in[2];
    const float* b0   = (const float*)d_in[3];
    const float* W1   = (const float*)d_in[4];
    const float* b1   = (const float*)d_in[5];
    const float* ws1  = (const float*)d_in[6];
    const float* ws2  = (const float*)d_in[7];
    const float* fc_w = (const float*)d_in[8];
    const float* fc_b = (const float*)d_in[9];

    float* out  = (float*)d_out;
    float* attn = out + (size_t)B_ * D_;
    (void)in_sizes; (void)n_in; (void)out_size;

    const int M = B_ * T_;
    char* ws = (char*)d_ws;

    // Tier A (unchunked): 181,141,632 B.  Tier B (CH=8): 80,478,336 B.
    const size_t NEED_A = 181141632ull;
    const size_t NEED_B = 80478336ull;
    const size_t NEED_FB = 100663424ull;

    if (ws_size >= NEED_B) {
        const int CHv = (ws_size >= NEED_A) ? 32 : 8;
        const size_t szU = (size_t)CHv * 512 * 3072 * 2;
        const size_t szX = (size_t)CHv * 512 * 1024 * 2;
        unsigned short* Uc   = (unsigned short*)ws;
        unsigned short* xbc  = (unsigned short*)(ws + szU);
        unsigned short* x2b  = (unsigned short*)(ws + szU + szX);
        unsigned short* W0p  = (unsigned short*)(ws + szU + szX + 33554432);
        unsigned short* W1p  = W0p + 3145728;
        unsigned short* ws1p = W1p + 3145728;
        int*            len  = (int*)(ws1p + 393216);
        // alias dead U' region after the chunk loop:
        float* hbar   = (float*)ws;                    // 22,937,600
        float* alph   = (float*)(ws + 22937600);       // 524,288
        float* pooled = (float*)(ws + 23461888);       // 1,048,576 (<= 25,165,824) OK

        lengths_k<<<B_, 512, 0, stream>>>(input, len);
        convW_k<false><<<(D_ * 3 * D_) / 256, 256, 0, stream>>>(W0, W0p, D_, 3 * D_, 24, 3 * D_);
        convW_k<false><<<(D_ * 3 * D_) / 256, 256, 0, stream>>>(W1, W1p, D_, 3 * D_, 24, 3 * D_);
        convW_k<true><<<(D_ * 384) / 256, 256, 0, stream>>>(ws1, ws1p, D_, 384, 3, HID_);

        for (int c0 = 0; c0 < B_; c0 += CHv) {
            const float* inC = input + (size_t)c0 * T_ * D_;
            const int Mc = CHv * T_;
            convX_k<<<(Mc * D_ / 4) / 256, 256, 0, stream>>>(inC, xbc);
            // Layer 1 (U' holds raw preactivations; sigmoid+bias applied in scan)
            gemm_mfma<0><<<dim3(24, Mc / 128), 256, 0, stream>>>(xbc, W0p, Uc, D_, 24, 0);
            sru_scan_seg<<<CHv * 16, 512, 0, stream>>>(Uc, b0, xbc, xbc);
            // Layer 2
            gemm_mfma<0><<<dim3(24, Mc / 128), 256, 0, stream>>>(xbc, W1p, Uc, D_, 24, 0);
            sru_scan_seg<<<CHv * 16, 512, 0, stream>>>(
                Uc, b1, xbc, x2b + (size_t)c0 * T_ * D_);
        }

        // hbar = tanh(x2 @ ws1^T) over full M (U' region now dead -> hbar)
        gemm_mfma<1><<<dim3(3, M / 128), 256, 0, stream>>>(x2b, ws1p, hbar, D_, 3, HID_);

        alphas_k<<<M / 256, 256, 0, stream>>>(hbar, ws2, alph);
        softmax_k<<<B_ * HOP_, 256, 0, stream>>>(alph, len, attn);
        pooled_bf_k<<<B_ * 4, 256, 0, stream>>>(attn, x2b, pooled);
        fc_k<<<D_ / 8, 256, 0, stream>>>(pooled, fc_w, fc_b, out);
        return;
    }

    // ---- fallback: chunked fp32 (round-2 proven) ----
    if (ws_size < NEED_FB) return;

    float* U    = (float*)ws;
    float* x1c  = (float*)(ws + 25165824);
    float* x2   = (float*)(ws + 33554432);
    int*   len  = (int*)(ws + 100663296);
    float* hbar   = (float*)ws;
    float* alph   = (float*)(ws + 22937600);
    float* pooled = (float*)(ws + 23461888);

    lengths_k<<<B_, 512, 0, stream>>>(input, len);

    const int Mc = CH_ * T_;
    for (int c0 = 0; c0 < B_; c0 += CH_) {
        const float* inC = input + (size_t)c0 * T_ * D_;
        float* x2C = x2 + (size_t)c0 * T_ * D_;
        gemm64<false, false><<<dim3(3 * D_ / 64, Mc / 64), 256, 0, stream>>>(
            inC, W0, U, Mc, 3 * D_, D_);
        sru_scan<<<CH_ * D_ / 256, 256, 0, stream>>>(U, b0, inC, x1c);
        gemm64<false, false><<<dim3(3 * D_ / 64, Mc / 64), 256, 0, stream>>>(
            x1c, W1, U, Mc, 3 * D_, D_);
        sru_scan<<<CH_ * D_ / 256, 256, 0, stream>>>(U, b1, x1c, x2C);
    }

    gemm64<true, true><<<dim3((HID_ + 63) / 64, M / 64), 256, 0, stream>>>(
        x2, ws1, hbar, M, HID_, D_);
    alphas_k<<<M / 256, 256, 0, stream>>>(hbar, ws2, alph);
    softmax_k<<<B_ * HOP_, 256, 0, stream>>>(alph, len, attn);
    pooled_k<<<B_ * 4, 256, 0, stream>>>(attn, x2, pooled);
    fc_k<<<D_ / 8, 256, 0, stream>>>(pooled, fc_w, fc_b, out);
}